// Round 1
// baseline (614.090 us; speedup 1.0000x reference)
//
#include <hip/hip_runtime.h>
#include <hip/hip_bf16.h>
#include <cstdint>
#include <cstddef>

// Problem constants (B=2, N=1024, C=512, H=8, hd=64, clusters=8)
#define NB   2
#define NN   1024
#define NC   512
#define NH   8
#define NHD  64
#define NK   8

typedef __attribute__((ext_vector_type(8))) short short8v;   // 8 bf16 (4 VGPRs)
typedef __attribute__((ext_vector_type(4))) short short4v;
typedef __attribute__((ext_vector_type(4))) float f32x4;

__device__ __forceinline__ short f2bf(float f) {
    union { float f; unsigned u; } v; v.f = f;
    unsigned r = v.u + 0x7FFFu + ((v.u >> 16) & 1u);   // RNE
    return (short)(r >> 16);
}

// ---------------------------------------------------------------- cast f32->bf16
__global__ __launch_bounds__(256) void cast_kernel(
    const float* __restrict__ x, const float* __restrict__ wq,
    const float* __restrict__ wk, const float* __restrict__ wv,
    const float* __restrict__ wp,
    short* __restrict__ xb, short* __restrict__ wqb, short* __restrict__ wkb,
    short* __restrict__ wvb, short* __restrict__ wpb) {
    int i = blockIdx.x * 256 + threadIdx.x;
    if (i < NB * NN * NC) xb[i] = f2bf(x[i]);
    if (i < NC * NC) {
        wqb[i] = f2bf(wq[i]);
        wkb[i] = f2bf(wk[i]);
        wvb[i] = f2bf(wv[i]);
        wpb[i] = f2bf(wp[i]);
    }
}

// ---------------------------------------------------------------- QKV GEMM
// q/k: (2048,512) bf16.  v stored transposed per head: vT[b,h,d,i] bf16.
__global__ __launch_bounds__(256) void qkv_kernel(
    const short* __restrict__ xb, const short* __restrict__ wqb,
    const short* __restrict__ wkb, const short* __restrict__ wvb,
    short* __restrict__ qb, short* __restrict__ kb, short* __restrict__ vT) {
    __shared__ short As[64][40];
    __shared__ short Bs[64][40];
    const int tid = threadIdx.x;
    const int z = blockIdx.z;
    const short* Bsrc = (z == 0) ? wqb : ((z == 1) ? wkb : wvb);
    const int m0 = blockIdx.y * 64, n0 = blockIdx.x * 64;
    const int lane = tid & 63, wave = tid >> 6;
    const int wm = wave >> 1, wn = wave & 1, quad = lane >> 4, lr = lane & 15;
    const int row = tid >> 2, c0 = (tid & 3) * 8;
    f32x4 acc[2][2] = {};
    for (int kt = 0; kt < 512; kt += 32) {
        *(short8v*)&As[row][c0] = *(const short8v*)(xb + (m0 + row) * 512 + kt + c0);
        *(short8v*)&Bs[row][c0] = *(const short8v*)(Bsrc + (n0 + row) * 512 + kt + c0);
        __syncthreads();
        short8v a0 = *(short8v*)&As[wm * 32 + lr][quad * 8];
        short8v a1 = *(short8v*)&As[wm * 32 + 16 + lr][quad * 8];
        short8v b0 = *(short8v*)&Bs[wn * 32 + lr][quad * 8];
        short8v b1 = *(short8v*)&Bs[wn * 32 + 16 + lr][quad * 8];
        acc[0][0] = __builtin_amdgcn_mfma_f32_16x16x32_bf16(a0, b0, acc[0][0], 0, 0, 0);
        acc[0][1] = __builtin_amdgcn_mfma_f32_16x16x32_bf16(a0, b1, acc[0][1], 0, 0, 0);
        acc[1][0] = __builtin_amdgcn_mfma_f32_16x16x32_bf16(a1, b0, acc[1][0], 0, 0, 0);
        acc[1][1] = __builtin_amdgcn_mfma_f32_16x16x32_bf16(a1, b1, acc[1][1], 0, 0, 0);
        __syncthreads();
    }
    for (int sm = 0; sm < 2; sm++)
        for (int sn = 0; sn < 2; sn++)
            for (int r = 0; r < 4; r++) {
                int m = m0 + wm * 32 + sm * 16 + quad * 4 + r;
                int n = n0 + wn * 32 + sn * 16 + lr;
                short v = f2bf(acc[sm][sn][r]);
                if (z == 0) qb[m * 512 + n] = v;
                else if (z == 1) kb[m * 512 + n] = v;
                else {
                    int bb = m >> 10, i = m & 1023, h = n >> 6, d = n & 63;
                    vT[(size_t)(((bb * 8 + h) * 64 + d) << 10) + i] = v;
                }
            }
}

// ---------------------------------------------------------------- scores s_ = scale * q k^T
// Writes raw f32 scores into the c=0 slice of attn_map (aliased scratch).
__global__ __launch_bounds__(256) void scores_kernel(
    const short* __restrict__ qb, const short* __restrict__ kb,
    float* __restrict__ attn) {
    __shared__ short As[64][72];
    __shared__ short Bs[64][72];
    const int tid = threadIdx.x;
    const int z = blockIdx.z;            // b*8 + h
    const int b = z >> 3, h = z & 7;
    const int i0 = blockIdx.y * 64, j0 = blockIdx.x * 64;
    const int lane = tid & 63, wave = tid >> 6;
    const int wm = wave >> 1, wn = wave & 1, quad = lane >> 4, lr = lane & 15;
    {
        int r0 = tid >> 3, cc = (tid & 7) * 8;
        *(short8v*)&As[r0][cc]      = *(const short8v*)(qb + (b * 1024 + i0 + r0) * 512 + h * 64 + cc);
        *(short8v*)&As[r0 + 32][cc] = *(const short8v*)(qb + (b * 1024 + i0 + r0 + 32) * 512 + h * 64 + cc);
        *(short8v*)&Bs[r0][cc]      = *(const short8v*)(kb + (b * 1024 + j0 + r0) * 512 + h * 64 + cc);
        *(short8v*)&Bs[r0 + 32][cc] = *(const short8v*)(kb + (b * 1024 + j0 + r0 + 32) * 512 + h * 64 + cc);
    }
    __syncthreads();
    f32x4 acc[2][2] = {};
    for (int k0 = 0; k0 < 64; k0 += 32) {
        short8v a0 = *(short8v*)&As[wm * 32 + lr][k0 + quad * 8];
        short8v a1 = *(short8v*)&As[wm * 32 + 16 + lr][k0 + quad * 8];
        short8v b0 = *(short8v*)&Bs[wn * 32 + lr][k0 + quad * 8];
        short8v b1 = *(short8v*)&Bs[wn * 32 + 16 + lr][k0 + quad * 8];
        acc[0][0] = __builtin_amdgcn_mfma_f32_16x16x32_bf16(a0, b0, acc[0][0], 0, 0, 0);
        acc[0][1] = __builtin_amdgcn_mfma_f32_16x16x32_bf16(a0, b1, acc[0][1], 0, 0, 0);
        acc[1][0] = __builtin_amdgcn_mfma_f32_16x16x32_bf16(a1, b0, acc[1][0], 0, 0, 0);
        acc[1][1] = __builtin_amdgcn_mfma_f32_16x16x32_bf16(a1, b1, acc[1][1], 0, 0, 0);
    }
    float* srow = attn + ((size_t)(b * 64 + h) << 20);   // c=0 slice, (N,N) per (b,h)
    for (int sm = 0; sm < 2; sm++)
        for (int sn = 0; sn < 2; sn++)
            for (int r = 0; r < 4; r++) {
                int i = i0 + wm * 32 + sm * 16 + quad * 4 + r;
                int j = j0 + wn * 32 + sn * 16 + lr;
                srow[((size_t)i << 10) + j] = acc[sm][sn][r] * 0.125f;
            }
}

// ---------------------------------------------------------------- row pass
// Reads raw score row (from c=0 slice), emits all 8 cluster rows of attn_map,
// computes eps-softmax, stores p (bf16) for the PV GEMM.
__global__ __launch_bounds__(256) void rowpass_kernel(
    const int* __restrict__ idx, float* __restrict__ attn,
    short* __restrict__ pb) {
    const int tid = threadIdx.x;
    const int bhi = blockIdx.x;          // (b*8+h)*1024 + i
    const int i = bhi & 1023, bh = bhi >> 10, b = bh >> 3, h = bh & 7;
    const int ci = idx[b * 1024 + i];
    const float* srow = attn + (((size_t)(b * 64 + h) << 10) + i) * 1024;
    float4 sv = ((const float4*)srow)[tid];
    int4 iv = ((const int4*)(idx + b * 1024))[tid];
    bool w0 = (iv.x == ci), w1 = (iv.y == ci), w2 = (iv.z == ci), w3 = (iv.w == ci);
    float e0 = (w0 && sv.x != 0.f) ? expf(sv.x) : 0.f;
    float e1 = (w1 && sv.y != 0.f) ? expf(sv.y) : 0.f;
    float e2 = (w2 && sv.z != 0.f) ? expf(sv.z) : 0.f;
    float e3 = (w3 && sv.w != 0.f) ? expf(sv.w) : 0.f;
    __shared__ float red[256];
    red[tid] = e0 + e1 + e2 + e3;
    __syncthreads();
    for (int s = 128; s > 0; s >>= 1) {
        if (tid < s) red[tid] += red[tid + s];
        __syncthreads();
    }
    const float inv = 1.f / (red[0] + 1e-6f);
    const float epsN = 1e-6f / 1024.f;
    short4v pv;
    pv[0] = f2bf((e0 + epsN) * inv);
    pv[1] = f2bf((e1 + epsN) * inv);
    pv[2] = f2bf((e2 + epsN) * inv);
    pv[3] = f2bf((e3 + epsN) * inv);
    *(short4v*)(pb + ((size_t)bhi << 10) + tid * 4) = pv;
    float4 masked;
    masked.x = w0 ? sv.x : 0.f;
    masked.y = w1 ? sv.y : 0.f;
    masked.z = w2 ? sv.z : 0.f;
    masked.w = w3 ? sv.w : 0.f;
    float4 zero4 = {0.f, 0.f, 0.f, 0.f};
    size_t base0 = (((size_t)(b * 64 + h) << 10) + i) * 1024 + tid * 4;   // c=0
    const size_t cstride = (size_t)8 * 1024 * 1024;                        // H*N*N
    for (int c = 0; c < 8; c++) {
        float4 wv = (c == ci) ? masked : zero4;
        *(float4*)(attn + base0 + (size_t)c * cstride) = wv;
    }
}

// ---------------------------------------------------------------- PV GEMM: oh = p @ v
__global__ __launch_bounds__(256) void pv_kernel(
    const short* __restrict__ pb, const short* __restrict__ vT,
    short* __restrict__ oh) {
    __shared__ short As[64][40];
    __shared__ short Bs[64][40];
    const int tid = threadIdx.x;
    const int z = blockIdx.z;            // b*8+h
    const int b = z >> 3, h = z & 7;
    const int i0 = blockIdx.y * 64;
    const int lane = tid & 63, wave = tid >> 6;
    const int wm = wave >> 1, wn = wave & 1, quad = lane >> 4, lr = lane & 15;
    const int row = tid >> 2, c0 = (tid & 3) * 8;
    const short* Abase = pb + ((size_t)(z * 1024 + i0) << 10);
    const short* Bbase = vT + ((size_t)z << 16);
    f32x4 acc[2][2] = {};
    for (int kt = 0; kt < 1024; kt += 32) {
        *(short8v*)&As[row][c0] = *(const short8v*)(Abase + ((size_t)row << 10) + kt + c0);
        *(short8v*)&Bs[row][c0] = *(const short8v*)(Bbase + ((size_t)row << 10) + kt + c0);
        __syncthreads();
        short8v a0 = *(short8v*)&As[wm * 32 + lr][quad * 8];
        short8v a1 = *(short8v*)&As[wm * 32 + 16 + lr][quad * 8];
        short8v b0 = *(short8v*)&Bs[wn * 32 + lr][quad * 8];
        short8v b1 = *(short8v*)&Bs[wn * 32 + 16 + lr][quad * 8];
        acc[0][0] = __builtin_amdgcn_mfma_f32_16x16x32_bf16(a0, b0, acc[0][0], 0, 0, 0);
        acc[0][1] = __builtin_amdgcn_mfma_f32_16x16x32_bf16(a0, b1, acc[0][1], 0, 0, 0);
        acc[1][0] = __builtin_amdgcn_mfma_f32_16x16x32_bf16(a1, b0, acc[1][0], 0, 0, 0);
        acc[1][1] = __builtin_amdgcn_mfma_f32_16x16x32_bf16(a1, b1, acc[1][1], 0, 0, 0);
        __syncthreads();
    }
    for (int sm = 0; sm < 2; sm++)
        for (int sn = 0; sn < 2; sn++)
            for (int r = 0; r < 4; r++) {
                int i = i0 + wm * 32 + sm * 16 + quad * 4 + r;
                int d = wn * 32 + sn * 16 + lr;
                oh[((size_t)(b * 1024 + i)) * 512 + h * 64 + d] = f2bf(acc[sm][sn][r]);
            }
}

// ---------------------------------------------------------------- proj GEMM + bias
__global__ __launch_bounds__(256) void proj_kernel(
    const short* __restrict__ oh, const short* __restrict__ wpb,
    const float* __restrict__ bias, float* __restrict__ out) {
    __shared__ short As[64][40];
    __shared__ short Bs[64][40];
    const int tid = threadIdx.x;
    const int m0 = blockIdx.y * 64, n0 = blockIdx.x * 64;
    const int lane = tid & 63, wave = tid >> 6;
    const int wm = wave >> 1, wn = wave & 1, quad = lane >> 4, lr = lane & 15;
    const int row = tid >> 2, c0 = (tid & 3) * 8;
    f32x4 acc[2][2] = {};
    for (int kt = 0; kt < 512; kt += 32) {
        *(short8v*)&As[row][c0] = *(const short8v*)(oh + (m0 + row) * 512 + kt + c0);
        *(short8v*)&Bs[row][c0] = *(const short8v*)(wpb + (n0 + row) * 512 + kt + c0);
        __syncthreads();
        short8v a0 = *(short8v*)&As[wm * 32 + lr][quad * 8];
        short8v a1 = *(short8v*)&As[wm * 32 + 16 + lr][quad * 8];
        short8v b0 = *(short8v*)&Bs[wn * 32 + lr][quad * 8];
        short8v b1 = *(short8v*)&Bs[wn * 32 + 16 + lr][quad * 8];
        acc[0][0] = __builtin_amdgcn_mfma_f32_16x16x32_bf16(a0, b0, acc[0][0], 0, 0, 0);
        acc[0][1] = __builtin_amdgcn_mfma_f32_16x16x32_bf16(a0, b1, acc[0][1], 0, 0, 0);
        acc[1][0] = __builtin_amdgcn_mfma_f32_16x16x32_bf16(a1, b0, acc[1][0], 0, 0, 0);
        acc[1][1] = __builtin_amdgcn_mfma_f32_16x16x32_bf16(a1, b1, acc[1][1], 0, 0, 0);
        __syncthreads();
    }
    for (int sm = 0; sm < 2; sm++)
        for (int sn = 0; sn < 2; sn++)
            for (int r = 0; r < 4; r++) {
                int m = m0 + wm * 32 + sm * 16 + quad * 4 + r;
                int n = n0 + wn * 32 + sn * 16 + lr;
                out[(size_t)m * 512 + n] = acc[sm][sn][r] + bias[n];
            }
}

// ---------------------------------------------------------------- launch
extern "C" void kernel_launch(void* const* d_in, const int* in_sizes, int n_in,
                              void* d_out, int out_size, void* d_ws, size_t ws_size,
                              hipStream_t stream) {
    const float* x     = (const float*)d_in[0];
    const int*   idx   = (const int*)d_in[2];
    const float* Wq    = (const float*)d_in[4];
    const float* Wk    = (const float*)d_in[5];
    const float* Wv    = (const float*)d_in[6];
    const float* Wp    = (const float*)d_in[7];
    const float* bproj = (const float*)d_in[8];

    float* out  = (float*)d_out;
    float* attn = out + (size_t)NB * NN * NC;   // attn_map region (B,K,H,N,N)

    char* ws = (char*)d_ws;
    short* xb  = (short*)(ws + 0);           // 2 MB
    short* wqb = (short*)(ws + 2097152);     // 512 KB
    short* wkb = (short*)(ws + 2621440);
    short* wvb = (short*)(ws + 3145728);
    short* wpb = (short*)(ws + 3670016);
    short* qb  = (short*)(ws + 4194304);     // 2 MB
    short* kb  = (short*)(ws + 6291456);     // 2 MB
    short* vT  = (short*)(ws + 8388608);     // 2 MB
    short* oh  = (short*)(ws + 10485760);    // 2 MB
    short* pb  = (short*)(ws + 12582912);    // 32 MB

    cast_kernel<<<4096, 256, 0, stream>>>(x, Wq, Wk, Wv, Wp, xb, wqb, wkb, wvb, wpb);
    qkv_kernel<<<dim3(8, 32, 3), 256, 0, stream>>>(xb, wqb, wkb, wvb, qb, kb, vT);
    scores_kernel<<<dim3(16, 16, 16), 256, 0, stream>>>(qb, kb, attn);
    rowpass_kernel<<<16384, 256, 0, stream>>>(idx, attn, pb);
    pv_kernel<<<dim3(1, 16, 16), 256, 0, stream>>>(pb, vT, oh);
    proj_kernel<<<dim3(8, 32, 1), 256, 0, stream>>>(oh, wpb, bproj, out);
}